// Round 9
// baseline (85.702 us; speedup 1.0000x reference)
//
#include <hip/hip_runtime.h>

// query_depth_point: B=8, N=16384, M=2048, NSAMPLE=64, DIS_Z=0.5
// Persistent: 256 blocks x 256 thr = 1024 waves (4 waves/CU, all co-resident
// at t=0, no dispatch ramp). Each wave statically owns 16 consecutive queries
// (same batch, 16 | 2048). Per query: scan 2048-candidate chunks; all 8
// float4 loads per chunk issued up front (ONE memory round-trip), then four
// 512-groups processed in order (candidate = cg + 8*lane + j, lexicographic
// in (lane,j)) with ballot + prefix-popcount ordered ranking and wave-uniform
// early exit at 64 matches. Consecutive queries reuse the L1-resident row.
// Outputs int32: idx (B,M,64) then pts_cnt (B,M).
// NOTE: timed window includes ~41.5 us of harness d_ws re-poison fill.

#define QDP_B 8
#define QDP_N 16384
#define QDP_M 2048
#define QDP_NS 64
#define QDP_DISZ 0.5f
#define QDP_QPW 16   // queries per wave

__device__ __forceinline__ void qdp_group(
    int cg, float zq, const float4& A, const float4& B,
    int lane, unsigned long long below,
    int& cnt, int& firstv, int* __restrict__ idx_out)
{
    const bool m0 = fabsf(A.x - zq) < QDP_DISZ;
    const bool m1 = fabsf(A.y - zq) < QDP_DISZ;
    const bool m2 = fabsf(A.z - zq) < QDP_DISZ;
    const bool m3 = fabsf(A.w - zq) < QDP_DISZ;
    const bool m4 = fabsf(B.x - zq) < QDP_DISZ;
    const bool m5 = fabsf(B.y - zq) < QDP_DISZ;
    const bool m6 = fabsf(B.z - zq) < QDP_DISZ;
    const bool m7 = fabsf(B.w - zq) < QDP_DISZ;

    const unsigned long long b0 = __ballot(m0);
    const unsigned long long b1 = __ballot(m1);
    const unsigned long long b2 = __ballot(m2);
    const unsigned long long b3 = __ballot(m3);
    const unsigned long long b4 = __ballot(m4);
    const unsigned long long b5 = __ballot(m5);
    const unsigned long long b6 = __ballot(m6);
    const unsigned long long b7 = __ballot(m7);
    const unsigned long long any = b0|b1|b2|b3|b4|b5|b6|b7;
    if (!any) return;                                   // wave-uniform

    const int mbyte = (int)m0 | ((int)m1<<1) | ((int)m2<<2) | ((int)m3<<3)
                    | ((int)m4<<4) | ((int)m5<<5) | ((int)m6<<6) | ((int)m7<<7);
    if (cnt == 0) {
        const int l0  = (int)__builtin_ctzll(any);
        const int mb0 = __shfl(mbyte, l0);
        firstv = cg + 8 * l0 + (int)__builtin_ctz((unsigned)mb0);
    }
    int r = cnt + __popcll(b0 & below) + __popcll(b1 & below)
                + __popcll(b2 & below) + __popcll(b3 & below)
                + __popcll(b4 & below) + __popcll(b5 & below)
                + __popcll(b6 & below) + __popcll(b7 & below);
    const int base = cg + 8 * lane;
    if (m0) { if (r < QDP_NS) idx_out[r] = base + 0; r++; }
    if (m1) { if (r < QDP_NS) idx_out[r] = base + 1; r++; }
    if (m2) { if (r < QDP_NS) idx_out[r] = base + 2; r++; }
    if (m3) { if (r < QDP_NS) idx_out[r] = base + 3; r++; }
    if (m4) { if (r < QDP_NS) idx_out[r] = base + 4; r++; }
    if (m5) { if (r < QDP_NS) idx_out[r] = base + 5; r++; }
    if (m6) { if (r < QDP_NS) idx_out[r] = base + 6; r++; }
    if (m7) { if (r < QDP_NS) idx_out[r] = base + 7; r++; }
    cnt += __popcll(b0) + __popcll(b1) + __popcll(b2) + __popcll(b3)
         + __popcll(b4) + __popcll(b5) + __popcll(b6) + __popcll(b7);
}

__global__ __launch_bounds__(256) void QueryDepthPoint_kernel(
    const float* __restrict__ xyz1,   // (B,3,N)
    const float* __restrict__ xyz2,   // (B,3,M)
    int* __restrict__ out_idx,        // (B,M,NS) int32
    int* __restrict__ out_cnt)        // (B,M)    int32
{
    const int lane = threadIdx.x & 63;
    const int wv   = (blockIdx.x << 2) + (threadIdx.x >> 6);   // 0..1023
    const unsigned long long below = (1ull << lane) - 1ull;

    const int qbase = wv * QDP_QPW;           // 16 consecutive queries
    const int b = qbase >> 11;                // same batch for all 16 (16 | 2048)
    const float* __restrict__ z1 = xyz1 + b * 3 * QDP_N + 2 * QDP_N;
    const float* __restrict__ z2 = xyz2 + b * 3 * QDP_M + 2 * QDP_M;

    // lanes 0..15 hold the 16 zq values (lanes 16+ duplicate; harmless)
    const float zqv = z2[(qbase & (QDP_M - 1)) + (lane & (QDP_QPW - 1))];

    #pragma unroll 1
    for (int k = 0; k < QDP_QPW; ++k) {
        const float zq = __shfl(zqv, k);
        int* __restrict__ idx_out = out_idx + (size_t)(qbase + k) * QDP_NS;
        int cnt = 0, firstv = 0;

        #pragma unroll 1
        for (int c = 0; c < QDP_N; c += 2048) {
            // issue all 8 loads (one round-trip); rows are L1-hot after query 0
            const float* p = z1 + c + 8 * lane;
            const float4 a0 = ((const float4*)p)[0];
            const float4 b0 = ((const float4*)p)[1];
            const float4 a1 = ((const float4*)(p + 512))[0];
            const float4 b1 = ((const float4*)(p + 512))[1];
            const float4 a2 = ((const float4*)(p + 1024))[0];
            const float4 b2 = ((const float4*)(p + 1024))[1];
            const float4 a3 = ((const float4*)(p + 1536))[0];
            const float4 b3 = ((const float4*)(p + 1536))[1];

            qdp_group(c +    0, zq, a0, b0, lane, below, cnt, firstv, idx_out);
            if (cnt >= QDP_NS) break;
            qdp_group(c +  512, zq, a1, b1, lane, below, cnt, firstv, idx_out);
            if (cnt >= QDP_NS) break;
            qdp_group(c + 1024, zq, a2, b2, lane, below, cnt, firstv, idx_out);
            if (cnt >= QDP_NS) break;
            qdp_group(c + 1536, zq, a3, b3, lane, below, cnt, firstv, idx_out);
            if (cnt >= QDP_NS) break;
        }
        if (cnt > QDP_NS) cnt = QDP_NS;

        // epilogue: trailing slots [cnt, 64) get first-match index (0 if none)
        if (lane >= cnt) idx_out[lane] = firstv;
        if (lane == 0)   out_cnt[qbase + k] = cnt;
    }
}

extern "C" void kernel_launch(void* const* d_in, const int* in_sizes, int n_in,
                              void* d_out, int out_size, void* d_ws, size_t ws_size,
                              hipStream_t stream) {
    const float* xyz1 = (const float*)d_in[0];   // (B,3,N) fp32
    const float* xyz2 = (const float*)d_in[1];   // (B,3,M) fp32
    int* out = (int*)d_out;                      // idx (B*M*64) then pts_cnt (B*M)

    int* out_idx = out;
    int* out_cnt = out + (size_t)QDP_B * QDP_M * QDP_NS;

    // 256 blocks x 4 waves = 1024 waves x 16 queries = 16384 queries.
    // 1 block/CU: fully co-resident, zero dispatch ramp.
    QueryDepthPoint_kernel<<<256, 256, 0, stream>>>(xyz1, xyz2, out_idx, out_cnt);
}

// Round 11
// 72.317 us; speedup vs baseline: 1.1851x; 1.1851x over previous
//
#include <hip/hip_runtime.h>

// query_depth_point: B=8, N=16384, M=2048, NSAMPLE=64, DIS_Z=0.5
// Wave-per-query (best structure: R5), 1024 candidates/iteration via 4
// independent float4 loads (one memory round-trip), processed as two
// 512-candidate groups (candidate = g + 8*lane + j, lexicographic in
// (lane,j)) with ballot + prefix-popcount ordered ranking and wave-uniform
// early exit between groups. Depth-1 prefetch with wrap addressing.
// Outputs int32: idx (B,M,64) then pts_cnt (B,M).
// NOTE: timed window includes ~41.5 us of harness d_ws re-poison fill +
// ~2-3 us of restore/memset graph nodes; kernel-attributable budget ~30 us.

#define QDP_B 8
#define QDP_N 16384
#define QDP_M 2048
#define QDP_NS 64
#define QDP_DISZ 0.5f

__device__ __forceinline__ void qdp_group(
    int g, float zq, const float4& A, const float4& B,
    int lane, unsigned long long below,
    int& cnt, int& firstv, int* __restrict__ idx_out)
{
    const bool m0 = fabsf(A.x - zq) < QDP_DISZ;
    const bool m1 = fabsf(A.y - zq) < QDP_DISZ;
    const bool m2 = fabsf(A.z - zq) < QDP_DISZ;
    const bool m3 = fabsf(A.w - zq) < QDP_DISZ;
    const bool m4 = fabsf(B.x - zq) < QDP_DISZ;
    const bool m5 = fabsf(B.y - zq) < QDP_DISZ;
    const bool m6 = fabsf(B.z - zq) < QDP_DISZ;
    const bool m7 = fabsf(B.w - zq) < QDP_DISZ;

    const unsigned long long b0 = __ballot(m0);
    const unsigned long long b1 = __ballot(m1);
    const unsigned long long b2 = __ballot(m2);
    const unsigned long long b3 = __ballot(m3);
    const unsigned long long b4 = __ballot(m4);
    const unsigned long long b5 = __ballot(m5);
    const unsigned long long b6 = __ballot(m6);
    const unsigned long long b7 = __ballot(m7);
    const unsigned long long any = b0|b1|b2|b3|b4|b5|b6|b7;
    if (!any) return;                                   // wave-uniform

    const int mbyte = (int)m0 | ((int)m1<<1) | ((int)m2<<2) | ((int)m3<<3)
                    | ((int)m4<<4) | ((int)m5<<5) | ((int)m6<<6) | ((int)m7<<7);
    if (cnt == 0) {
        const int l0  = (int)__builtin_ctzll(any);
        const int mb0 = __shfl(mbyte, l0);
        firstv = g + 8 * l0 + (int)__builtin_ctz((unsigned)mb0);
    }
    int r = cnt + __popcll(b0 & below) + __popcll(b1 & below)
                + __popcll(b2 & below) + __popcll(b3 & below)
                + __popcll(b4 & below) + __popcll(b5 & below)
                + __popcll(b6 & below) + __popcll(b7 & below);
    const int base = g + 8 * lane;
    if (m0) { if (r < QDP_NS) idx_out[r] = base + 0; r++; }
    if (m1) { if (r < QDP_NS) idx_out[r] = base + 1; r++; }
    if (m2) { if (r < QDP_NS) idx_out[r] = base + 2; r++; }
    if (m3) { if (r < QDP_NS) idx_out[r] = base + 3; r++; }
    if (m4) { if (r < QDP_NS) idx_out[r] = base + 4; r++; }
    if (m5) { if (r < QDP_NS) idx_out[r] = base + 5; r++; }
    if (m6) { if (r < QDP_NS) idx_out[r] = base + 6; r++; }
    if (m7) { if (r < QDP_NS) idx_out[r] = base + 7; r++; }
    cnt += __popcll(b0) + __popcll(b1) + __popcll(b2) + __popcll(b3)
         + __popcll(b4) + __popcll(b5) + __popcll(b6) + __popcll(b7);
}

__global__ __launch_bounds__(256) void QueryDepthPoint_kernel(
    const float* __restrict__ xyz1,   // (B,3,N)
    const float* __restrict__ xyz2,   // (B,3,M)
    int* __restrict__ out_idx,        // (B,M,NS) int32
    int* __restrict__ out_cnt)        // (B,M)    int32
{
    const int lane = threadIdx.x & 63;
    const int wid  = (blockIdx.x << 2) + (threadIdx.x >> 6);   // 4 waves/block

    const int b = wid >> 11;            // wid / M  (M = 2048)
    const int q = wid & (QDP_M - 1);    // wid % M

    const float zq = xyz2[b * 3 * QDP_M + 2 * QDP_M + q];
    const float* __restrict__ z1 = xyz1 + b * 3 * QDP_N + 2 * QDP_N;
    int* __restrict__ idx_out = out_idx + (size_t)wid * QDP_NS;

    int cnt = 0, firstv = 0;
    const unsigned long long below = (1ull << lane) - 1ull;
    const int lo = 8 * lane;            // lane's offset within a 512-group

    // prefetch chunk 0: 1024 candidates via 4 independent 16B loads
    float4 cA0 = ((const float4*)(z1 + lo))[0];
    float4 cB0 = ((const float4*)(z1 + lo))[1];
    float4 cA1 = ((const float4*)(z1 + 512 + lo))[0];
    float4 cB1 = ((const float4*)(z1 + 512 + lo))[1];

    #pragma unroll 1   // 16 trips x large body: do not unroll
    for (int c = 0; c < QDP_N; c += 1024) {
        const int pn = (c + 1024) & (QDP_N - 1);   // wrap: always in-bounds
        float4 nA0 = ((const float4*)(z1 + pn + lo))[0];
        float4 nB0 = ((const float4*)(z1 + pn + lo))[1];
        float4 nA1 = ((const float4*)(z1 + pn + 512 + lo))[0];
        float4 nB1 = ((const float4*)(z1 + pn + 512 + lo))[1];

        qdp_group(c,       zq, cA0, cB0, lane, below, cnt, firstv, idx_out);
        if (cnt >= QDP_NS) break;
        qdp_group(c + 512, zq, cA1, cB1, lane, below, cnt, firstv, idx_out);
        if (cnt >= QDP_NS) break;

        cA0 = nA0; cB0 = nB0; cA1 = nA1; cB1 = nB1;
    }
    if (cnt > QDP_NS) cnt = QDP_NS;

    // trailing slots [cnt, 64) get the first-match index (0 if no match)
    if (lane >= cnt) idx_out[lane] = firstv;
    if (lane == 0)   out_cnt[wid] = cnt;
}

extern "C" void kernel_launch(void* const* d_in, const int* in_sizes, int n_in,
                              void* d_out, int out_size, void* d_ws, size_t ws_size,
                              hipStream_t stream) {
    const float* xyz1 = (const float*)d_in[0];   // (B,3,N) fp32
    const float* xyz2 = (const float*)d_in[1];   // (B,3,M) fp32
    int* out = (int*)d_out;                      // idx (B*M*64) then pts_cnt (B*M)

    int* out_idx = out;
    int* out_cnt = out + (size_t)QDP_B * QDP_M * QDP_NS;

    const int total_waves = QDP_B * QDP_M;           // 16384 queries
    const int grid = total_waves / 4;                // 4 waves (256 thr) per block

    QueryDepthPoint_kernel<<<grid, 256, 0, stream>>>(xyz1, xyz2, out_idx, out_cnt);
}